// Round 12
// baseline (265.382 us; speedup 1.0000x reference)
//
#include <hip/hip_runtime.h>

#define N 4096
#define NB 32      // N / 128
#define CH 16      // split-K chunk = CH 128-blocks (R10 champion policy)

typedef __bf16 bf16;
typedef bf16 bf16x4 __attribute__((ext_vector_type(4)));
typedef bf16 bf16x8 __attribute__((ext_vector_type(8)));
typedef float f32x4 __attribute__((ext_vector_type(4)));

__device__ __host__ __forceinline__ constexpr int tri(int i) { return (i * (i + 1)) >> 1; }

// async global(16B) -> LDS, wave-uniform LDS base + lane*16
__device__ __forceinline__ void async16(const bf16* g, const bf16* l) {
    __builtin_amdgcn_global_load_lds(
        (const __attribute__((address_space(1))) unsigned int*)g,
        (__attribute__((address_space(3))) unsigned int*)l, 16, 0, 0);
}

// ---- fused prepass: A -> tri-compacted bf16 128x128 tiles [m][k],
// B -> tri-compacted TRANSPOSED tiles [n][k]; B global stores coalesced via
// LDS transpose (round 2). Block (0,0) also zeroes the 136 split-tile
// counters (stream order guarantees visibility to tril_mm).
__global__ __launch_bounds__(256) void conv_ab(const float* __restrict__ A,
                                               const float* __restrict__ B,
                                               bf16* __restrict__ Abf,
                                               bf16* __restrict__ Btf,
                                               int* __restrict__ cnt) {
    __shared__ __align__(16) bf16 T[128 * 136];    // B-transpose staging, pad 136
    const int x = blockIdx.x, y = blockIdx.y;
    const int tid = threadIdx.x;
    if (cnt && x == 0 && y == 0 && tid < 136) cnt[tid] = 0;
    if (y < NB) {
        const int bi = y, bk = x;
        if (bk > bi) return;
        bf16* slot = Abf + (size_t)(tri(bi) + bk) * 16384;
#pragma unroll
        for (int it = 0; it < 8; ++it) {
            const int c = it * 256 + tid;
            const int row = c >> 4, col8 = c & 15;
            const float* src = &A[(size_t)(bi * 128 + row) * N + bk * 128 + col8 * 8];
            f32x4 v0 = *(const f32x4*)src;
            f32x4 v1 = *(const f32x4*)(src + 4);
            bf16x8 h = { (bf16)v0[0], (bf16)v0[1], (bf16)v0[2], (bf16)v0[3],
                         (bf16)v1[0], (bf16)v1[1], (bf16)v1[2], (bf16)v1[3] };
            *(bf16x8*)&slot[row * 128 + col8 * 8] = h;
        }
    } else {
        const int bn = y - NB, bk = x;
        if (bk < bn) return;
        bf16* slot = Btf + (size_t)(tri(bk) + bn) * 16384;
        const int kq = tid >> 5;
        const int n4 = tid & 31;
#pragma unroll
        for (int it = 0; it < 4; ++it) {
            const int kl = it * 32 + kq * 4;
            const float* src = &B[(size_t)(bk * 128 + kl) * N + bn * 128 + n4 * 4];
            f32x4 r0 = *(const f32x4*)(src + 0 * N);
            f32x4 r1 = *(const f32x4*)(src + 1 * N);
            f32x4 r2 = *(const f32x4*)(src + 2 * N);
            f32x4 r3 = *(const f32x4*)(src + 3 * N);
#pragma unroll
            for (int i = 0; i < 4; ++i) {
                bf16x4 h = { (bf16)r0[i], (bf16)r1[i], (bf16)r2[i], (bf16)r3[i] };
                *(bf16x4*)&T[(n4 * 4 + i) * 136 + kl] = h;
            }
        }
        __syncthreads();
#pragma unroll
        for (int it = 0; it < 8; ++it) {
            const int idx = it * 256 + tid;
            const int nn = idx >> 4, k8 = idx & 15;
            *(bf16x8*)&slot[nn * 128 + k8 * 8] = *(const bf16x8*)&T[nn * 136 + k8 * 8];
        }
    }
}

// ---- main: R10 champion (CH16 schedule, single-buffer 32 KB loop, partials)
// with ONE change: reduce_k is FOLDED into the epilogue. Both pieces of a
// split tile write their 64 KB f32 partial (plain cached stores), then
// threadfence + syncthreads + tid0 atomicAdd on the per-tile counter
// (device scope, cross-XCD safe [m20]); the second-to-arrive piece acquire-
// fences, reads its sibling's partial, adds its own in-register acc, and
// writes C once (nontemporal). Saves the serial 300-block reduce launch and
// its C-pass; adds only 136 atomics (no feed poisoning -- R10 proved the
// damage scales with Matomics). Fallback (no ws): all-pieces atomicAdd.
__global__ __launch_bounds__(256) void tril_mm_kernel(const bf16* __restrict__ Abf,
                                                      const bf16* __restrict__ Btf,
                                                      float* __restrict__ C,
                                                      float* __restrict__ part,
                                                      int* __restrict__ cnt) {
    // decode unit id -> (d, bj, chunk); descending d so long chains start
    // first. psum counts split pieces in d' > d.
    int id = blockIdx.x;
    int d = NB - 1, psum = 0;
    for (; d > 0; --d) {
        const int c0 = (NB - d) * ((d >> 4) + 1);
        if (id < c0) break;
        id -= c0;
        if (d >= 16) psum += c0;
    }
    const int S = (d >> 4) + 1;
    const int bj = id / S;
    const int cidx = id - bj * S;
    const int bi = bj + d;

    const int kb_start = bj + cidx * CH;
    const int kb_end   = min(kb_start + CH, bi + 1);
    const int triBi = tri(bi);

    __shared__ __align__(16) bf16 As[128 * 64];   // 16 KB
    __shared__ __align__(16) bf16 Bs[128 * 64];   // 16 KB
    __shared__ int s_last;

    const int tid = threadIdx.x;
    const int wave = tid >> 6;
    const int wm = (wave >> 1) * 64;
    const int wn = (wave & 1) * 64;
    const int l15 = tid & 15;
    const int quad = (tid & 63) >> 4;
    const int wbase = tid & ~63;

    // per-lane global chunk offsets for staging (inverse swizzle)
    int goff[4];
#pragma unroll
    for (int t = 0; t < 4; ++t) {
        const int s = t * 256 + tid;
        const int row = s >> 3;
        const int kg = (s & 7) ^ (row & 7);
        goff[t] = row * 128 + kg * 8;
    }
    // fragment LDS chunk indices
    int ach[4][2], bch[4][2];
#pragma unroll
    for (int i = 0; i < 4; ++i)
#pragma unroll
        for (int h = 0; h < 2; ++h) {
            const int m = wm + i * 16 + l15;
            const int n = wn + i * 16 + l15;
            const int kg = h * 4 + quad;
            ach[i][h] = m * 8 + (kg ^ (m & 7));
            bch[i][h] = n * 8 + (kg ^ (n & 7));
        }

    f32x4 acc[4][4] = {};

    for (int kb = kb_start; kb < kb_end; ++kb) {
        const bf16* Ab = Abf + (size_t)(triBi + kb) * 16384;
        const bf16* Bb = Btf + (size_t)(tri(kb) + bj) * 16384;
#pragma unroll
        for (int kk = 0; kk < 128; kk += 64) {
#pragma unroll
            for (int t = 0; t < 4; ++t) {
                async16(Ab + kk + goff[t], &As[(t * 256 + wbase) * 8]);
                async16(Bb + kk + goff[t], &Bs[(t * 256 + wbase) * 8]);
            }
            __syncthreads();
#pragma unroll
            for (int h = 0; h < 2; ++h) {
                bf16x8 af[4], bfr[4];
#pragma unroll
                for (int i = 0; i < 4; ++i) {
                    af[i]  = *(const bf16x8*)&As[ach[i][h] * 8];
                    bfr[i] = *(const bf16x8*)&Bs[bch[i][h] * 8];
                }
#pragma unroll
                for (int i = 0; i < 4; ++i)
#pragma unroll
                    for (int j = 0; j < 4; ++j)
                        acc[i][j] = __builtin_amdgcn_mfma_f32_16x16x32_bf16(af[i], bfr[j], acc[i][j], 0, 0, 0);
            }
            __syncthreads();
        }
    }

    // epilogue: C/D layout col = lane&15, row = quad*4 + v.
    const int row0 = bi * 128, col0 = bj * 128;
    if (S == 1) {
        // exact triangular inputs give exact zeros above the diagonal ->
        // unpredicated nontemporal stores safe (C write-once).
#pragma unroll
        for (int i = 0; i < 4; ++i)
#pragma unroll
            for (int j = 0; j < 4; ++j) {
                const int colg = col0 + wn + j * 16 + l15;
#pragma unroll
                for (int v = 0; v < 4; ++v) {
                    const int rowg = row0 + wm + i * 16 + quad * 4 + v;
                    __builtin_nontemporal_store(acc[i][j][v], &C[(size_t)rowg * N + colg]);
                }
            }
    } else if (part) {
        // write my partial (plain stores: keep in L2/L3 for the sibling)
        float* p = part + (size_t)(psum + id) * 16384;
#pragma unroll
        for (int i = 0; i < 4; ++i)
#pragma unroll
            for (int j = 0; j < 4; ++j) {
                const int colt = wn + j * 16 + l15;
#pragma unroll
                for (int v = 0; v < 4; ++v) {
                    const int rowt = wm + i * 16 + quad * 4 + v;
                    p[rowt * 128 + colt] = acc[i][j][v];
                }
            }
        __threadfence();               // release my stores to device scope
        __syncthreads();               // all waves of this block committed
        if (tid == 0) s_last = atomicAdd(&cnt[(psum >> 1) + bj], 1);
        __syncthreads();
        if (s_last == 1) {             // I'm the second (last) piece
            __threadfence();           // acquire: invalidate stale L2 lines
            const float* q = part + (size_t)(psum + bj * 2 + (1 - cidx)) * 16384;
#pragma unroll
            for (int i = 0; i < 4; ++i)
#pragma unroll
                for (int j = 0; j < 4; ++j) {
                    const int colt = wn + j * 16 + l15;
                    const int colg = col0 + colt;
#pragma unroll
                    for (int v = 0; v < 4; ++v) {
                        const int rowt = wm + i * 16 + quad * 4 + v;
                        const float r = acc[i][j][v] + q[rowt * 128 + colt];
                        __builtin_nontemporal_store(r, &C[(size_t)(row0 + rowt) * N + colg]);
                    }
                }
        }
    } else {
        // no-workspace fallback: atomicAdd onto poison (verified passing).
#pragma unroll
        for (int i = 0; i < 4; ++i)
#pragma unroll
            for (int j = 0; j < 4; ++j) {
                const int colg = col0 + wn + j * 16 + l15;
#pragma unroll
                for (int v = 0; v < 4; ++v) {
                    const int rowg = row0 + wm + i * 16 + quad * 4 + v;
                    atomicAdd(&C[(size_t)rowg * N + colg], acc[i][j][v]);
                }
            }
    }
}

extern "C" void kernel_launch(void* const* d_in, const int* in_sizes, int n_in,
                              void* d_out, int out_size, void* d_ws, size_t ws_size,
                              hipStream_t stream) {
    const float* A = (const float*)d_in[0];
    const float* B = (const float*)d_in[1];
    float* C = (float*)d_out;
    bf16* Abf = (bf16*)d_ws;                       // 528 tiles x 32 KB = 16.5 MiB
    bf16* Btf = Abf + (size_t)528 * 16384;         // another 16.5 MiB
    float* part = (float*)(Btf + (size_t)528 * 16384);   // 272 x 64 KB = 17 MiB
    int* cnt = (int*)(part + (size_t)272 * 16384);       // 136 counters

    const size_t need = (size_t)528 * 2 * 16384 * 2 + (size_t)272 * 16384 * 4 + 136 * 4;
    const bool use_part = ws_size >= need;

    int units = 0;
    for (int d = 0; d < NB; ++d) units += (NB - d) * ((d >> 4) + 1);  // = 664

    conv_ab<<<dim3(NB, 2 * NB), dim3(256), 0, stream>>>(A, B, Abf, Btf,
                                                        use_part ? cnt : nullptr);
    tril_mm_kernel<<<dim3(units), dim3(256), 0, stream>>>(Abf, Btf, C,
                                                          use_part ? part : nullptr,
                                                          use_part ? cnt : nullptr);
}